// Round 1
// baseline (2664.266 us; speedup 1.0000x reference)
//
#include <hip/hip_runtime.h>
#include <hip/hip_bf16.h>

#define HID 64
#define L 3

// out[r][j] = (bias ? bias[j] : 0) + sum_k in[r][k] * W[k*64+j]
// Row-per-thread; W accesses are wave-uniform -> scalar loads (s_load) + FMA w/ SGPR operand.
__global__ __launch_bounds__(256, 1) void k_matmul64(
    const float* __restrict__ in, const float* __restrict__ W,
    const float* __restrict__ bias, float* __restrict__ out, int N)
{
    int r = blockIdx.x * 256 + threadIdx.x;
    if (r >= N) return;
    float x[64];
    const float4* rp = (const float4*)(in + (size_t)r * 64);
#pragma unroll
    for (int q = 0; q < 16; q++) {
        float4 v = rp[q];
        x[4*q+0] = v.x; x[4*q+1] = v.y; x[4*q+2] = v.z; x[4*q+3] = v.w;
    }
    float u[64];
#pragma unroll
    for (int j = 0; j < 64; j++) u[j] = bias ? bias[j] : 0.0f;
    for (int k = 0; k < 64; k++) {
        float xk = x[k];
#pragma unroll
        for (int j = 0; j < 64; j++) u[j] += xk * W[k*64 + j];
    }
    float4* op = (float4*)(out + (size_t)r * 64);
#pragma unroll
    for (int q = 0; q < 16; q++)
        op[q] = make_float4(u[4*q+0], u[4*q+1], u[4*q+2], u[4*q+3]);
}

// Fused GIN node update:
// x = (1+eps)*h + neigh
// t = relu(bn1(x@W1 + b1)); u = t@W2 + b2; u = relu(bn_a(u)); u = relu(bn_g(u));
// h = h + u   (in place, row-per-thread)
__global__ __launch_bounds__(256, 1) void k_gin_update(
    float* __restrict__ h, const float* __restrict__ neigh,
    const float* __restrict__ epsp,
    const float* __restrict__ W1, const float* __restrict__ b1,
    const float* __restrict__ s1, const float* __restrict__ sh1,
    const float* __restrict__ W2, const float* __restrict__ b2,
    const float* __restrict__ as_, const float* __restrict__ ash,
    const float* __restrict__ gs, const float* __restrict__ gsh, int N)
{
    int r = blockIdx.x * 256 + threadIdx.x;
    if (r >= N) return;
    float epsv = 1.0f + epsp[0];
    float x[64];
    const float4* hp = (const float4*)(h + (size_t)r * 64);
    const float4* np = (const float4*)(neigh + (size_t)r * 64);
#pragma unroll
    for (int q = 0; q < 16; q++) {
        float4 hv = hp[q], nv = np[q];
        x[4*q+0] = epsv * hv.x + nv.x;
        x[4*q+1] = epsv * hv.y + nv.y;
        x[4*q+2] = epsv * hv.z + nv.z;
        x[4*q+3] = epsv * hv.w + nv.w;
    }
    float t[64];
#pragma unroll
    for (int j = 0; j < 64; j++) t[j] = b1[j];
    for (int k = 0; k < 64; k++) {
        float xk = x[k];
#pragma unroll
        for (int j = 0; j < 64; j++) t[j] += xk * W1[k*64 + j];
    }
#pragma unroll
    for (int j = 0; j < 64; j++) {
        float v = t[j] * s1[j] + sh1[j];
        t[j] = v > 0.0f ? v : 0.0f;
    }
    float u[64];
#pragma unroll
    for (int j = 0; j < 64; j++) u[j] = b2[j];
    for (int k = 0; k < 64; k++) {
        float tk = t[k];
#pragma unroll
        for (int j = 0; j < 64; j++) u[j] += tk * W2[k*64 + j];
    }
#pragma unroll
    for (int j = 0; j < 64; j++) {
        float v = u[j] * as_[j] + ash[j];
        v = v > 0.0f ? v : 0.0f;
        v = v * gs[j] + gsh[j];
        u[j] = v > 0.0f ? v : 0.0f;
    }
    float4* hw = (float4*)(h + (size_t)r * 64);
#pragma unroll
    for (int q = 0; q < 16; q++) {
        float4 hv = hp[q];
        hw[q] = make_float4(hv.x + u[4*q+0], hv.y + u[4*q+1],
                            hv.z + u[4*q+2], hv.w + u[4*q+3]);
    }
}

// Fused edge kernel: score head (A[src]+B[dst]+e@Wc -> relu -> dot W2 -> +b2)
// and (if AGG) GIN sum aggregation neigh[dst] += h[src].
// 16 lanes per edge, lane li owns features [4*li, 4*li+4).
// MODE 0: score = val; MODE 1: score += val; MODE 2: score = relu(score + val)
template <int MODE, int AGG>
__global__ __launch_bounds__(256, 4) void k_edge(
    const float* __restrict__ A, const float* __restrict__ Bm,
    const float* __restrict__ hcur, const float* __restrict__ e,
    const int* __restrict__ src, const int* __restrict__ dst,
    const float* __restrict__ Wc,   // rows 128..129 of pred_W1[i]: [2][64]
    const float* __restrict__ W2,   // [64]
    const float* __restrict__ b2p,  // [1]
    float* __restrict__ neigh, float* __restrict__ score, int E)
{
    const int li = threadIdx.x & 15;
    const float4 wc0 = *(const float4*)(Wc + li*4);
    const float4 wc1 = *(const float4*)(Wc + 64 + li*4);
    const float4 w2  = *(const float4*)(W2 + li*4);
    const float b2 = b2p[0];
    int g  = (blockIdx.x * 256 + threadIdx.x) >> 4;
    int ng = (gridDim.x * 256) >> 4;
    for (int idx = g; idx < E; idx += ng) {
        int s = src[idx];
        int d = dst[idx];
        float2 ev = *(const float2*)(e + 2*(size_t)idx);
        float4 a = *(const float4*)(A  + (size_t)s*64 + li*4);
        float4 b = *(const float4*)(Bm + (size_t)d*64 + li*4);
        float z0 = a.x + b.x + ev.x*wc0.x + ev.y*wc1.x; z0 = z0 > 0.f ? z0 : 0.f;
        float z1 = a.y + b.y + ev.x*wc0.y + ev.y*wc1.y; z1 = z1 > 0.f ? z1 : 0.f;
        float z2 = a.z + b.z + ev.x*wc0.z + ev.y*wc1.z; z2 = z2 > 0.f ? z2 : 0.f;
        float z3 = a.w + b.w + ev.x*wc0.w + ev.y*wc1.w; z3 = z3 > 0.f ? z3 : 0.f;
        float p = z0*w2.x + z1*w2.y + z2*w2.z + z3*w2.w;
        p += __shfl_xor(p, 1);
        p += __shfl_xor(p, 2);
        p += __shfl_xor(p, 4);
        p += __shfl_xor(p, 8);
        if (li == 0) {
            if (MODE == 0) {
                score[idx] = p + b2;
            } else if (MODE == 1) {
                score[idx] += p + b2;
            } else {
                float v = score[idx] + p + b2;
                score[idx] = v > 0.f ? v : 0.f;
            }
        }
        if (AGG) {
            float4 hv = *(const float4*)(hcur + (size_t)s*64 + li*4);
            float* npp = neigh + (size_t)d*64 + li*4;
            atomicAdd(npp + 0, hv.x);
            atomicAdd(npp + 1, hv.y);
            atomicAdd(npp + 2, hv.z);
            atomicAdd(npp + 3, hv.w);
        }
    }
}

extern "C" void kernel_launch(void* const* d_in, const int* in_sizes, int n_in,
                              void* d_out, int out_size, void* d_ws, size_t ws_size,
                              hipStream_t stream) {
    const float* h_in  = (const float*)d_in[0];
    const float* e     = (const float*)d_in[1];
    const int*   src   = (const int*)d_in[2];
    const int*   dst   = (const int*)d_in[3];
    const float* emb_W = (const float*)d_in[4];
    const float* emb_b = (const float*)d_in[5];
    const float* eps   = (const float*)d_in[6];
    const float* mW1   = (const float*)d_in[7];
    const float* mb1   = (const float*)d_in[8];
    const float* mbs   = (const float*)d_in[9];
    const float* mbsh  = (const float*)d_in[10];
    const float* mW2   = (const float*)d_in[11];
    const float* mb2   = (const float*)d_in[12];
    const float* as_   = (const float*)d_in[13];
    const float* ash   = (const float*)d_in[14];
    const float* gs    = (const float*)d_in[15];
    const float* gsh   = (const float*)d_in[16];
    const float* pW1   = (const float*)d_in[17];
    const float* pb1   = (const float*)d_in[18];
    const float* pW2   = (const float*)d_in[19];
    const float* pb2   = (const float*)d_in[20];

    const int N = in_sizes[0] / 64;
    const int E = in_sizes[2];

    float* score = (float*)d_out;
    float* ws    = (float*)d_ws;
    float* hcur  = ws;
    float* neigh = ws + (size_t)N * 64;
    float* Abuf  = ws + 2 * (size_t)N * 64;
    float* Bbuf  = ws + 3 * (size_t)N * 64;

    const int nodeBlocks = (N + 255) / 256;
    const int edgeBlocks = 2048;

    // h = h_in @ emb_W + emb_b
    k_matmul64<<<nodeBlocks, 256, 0, stream>>>(h_in, emb_W, emb_b, hcur, N);

    for (int i = 0; i <= L; i++) {
        const float* pw = pW1 + (size_t)i * 130 * 64;
        // A = h @ pw[0:64]   + pb1[i];  B = h @ pw[64:128]
        k_matmul64<<<nodeBlocks, 256, 0, stream>>>(hcur, pw, pb1 + i*64, Abuf, N);
        k_matmul64<<<nodeBlocks, 256, 0, stream>>>(hcur, pw + 64*64, nullptr, Bbuf, N);

        if (i < L) {
            hipMemsetAsync(neigh, 0, (size_t)N * 64 * sizeof(float), stream);
        }

        const float* Wc = pw + 128 * 64;
        const float* w2 = pW2 + (size_t)i * 64;
        const float* b2 = pb2 + i;
        if (i == 0) {
            k_edge<0, 1><<<edgeBlocks, 256, 0, stream>>>(Abuf, Bbuf, hcur, e, src, dst,
                                                         Wc, w2, b2, neigh, score, E);
        } else if (i < L) {
            k_edge<1, 1><<<edgeBlocks, 256, 0, stream>>>(Abuf, Bbuf, hcur, e, src, dst,
                                                         Wc, w2, b2, neigh, score, E);
        } else {
            k_edge<2, 0><<<edgeBlocks, 256, 0, stream>>>(Abuf, Bbuf, hcur, e, src, dst,
                                                         Wc, w2, b2, neigh, score, E);
        }

        if (i < L) {
            k_gin_update<<<nodeBlocks, 256, 0, stream>>>(
                hcur, neigh, eps + i,
                mW1 + (size_t)i*64*64, mb1 + i*64, mbs + i*64, mbsh + i*64,
                mW2 + (size_t)i*64*64, mb2 + i*64,
                as_ + i*64, ash + i*64, gs + i*64, gsh + i*64, N);
        }
    }
}

// Round 2
// 1071.981 us; speedup vs baseline: 2.4854x; 2.4854x over previous
//
#include <hip/hip_runtime.h>
#include <hip/hip_bf16.h>

#define HID 64
#define L 3

// out[r][j] = (bias ? bias[j] : 0) + sum_k in[r][k] * W[k*64+j]
__global__ __launch_bounds__(256, 1) void k_matmul64(
    const float* __restrict__ in, const float* __restrict__ W,
    const float* __restrict__ bias, float* __restrict__ out, int N)
{
    int r = blockIdx.x * 256 + threadIdx.x;
    if (r >= N) return;
    float x[64];
    const float4* rp = (const float4*)(in + (size_t)r * 64);
#pragma unroll
    for (int q = 0; q < 16; q++) {
        float4 v = rp[q];
        x[4*q+0] = v.x; x[4*q+1] = v.y; x[4*q+2] = v.z; x[4*q+3] = v.w;
    }
    float u[64];
#pragma unroll
    for (int j = 0; j < 64; j++) u[j] = bias ? bias[j] : 0.0f;
    for (int k = 0; k < 64; k++) {
        float xk = x[k];
#pragma unroll
        for (int j = 0; j < 64; j++) u[j] += xk * W[k*64 + j];
    }
    float4* op = (float4*)(out + (size_t)r * 64);
#pragma unroll
    for (int q = 0; q < 16; q++)
        op[q] = make_float4(u[4*q+0], u[4*q+1], u[4*q+2], u[4*q+3]);
}

// Fused GIN node update (in-place on h).
__global__ __launch_bounds__(256, 1) void k_gin_update(
    float* __restrict__ h, const float* __restrict__ neigh,
    const float* __restrict__ epsp,
    const float* __restrict__ W1, const float* __restrict__ b1,
    const float* __restrict__ s1, const float* __restrict__ sh1,
    const float* __restrict__ W2, const float* __restrict__ b2,
    const float* __restrict__ as_, const float* __restrict__ ash,
    const float* __restrict__ gs, const float* __restrict__ gsh, int N)
{
    int r = blockIdx.x * 256 + threadIdx.x;
    if (r >= N) return;
    float epsv = 1.0f + epsp[0];
    float x[64];
    const float4* hp = (const float4*)(h + (size_t)r * 64);
    const float4* np = (const float4*)(neigh + (size_t)r * 64);
#pragma unroll
    for (int q = 0; q < 16; q++) {
        float4 hv = hp[q], nv = np[q];
        x[4*q+0] = epsv * hv.x + nv.x;
        x[4*q+1] = epsv * hv.y + nv.y;
        x[4*q+2] = epsv * hv.z + nv.z;
        x[4*q+3] = epsv * hv.w + nv.w;
    }
    float t[64];
#pragma unroll
    for (int j = 0; j < 64; j++) t[j] = b1[j];
    for (int k = 0; k < 64; k++) {
        float xk = x[k];
#pragma unroll
        for (int j = 0; j < 64; j++) t[j] += xk * W1[k*64 + j];
    }
#pragma unroll
    for (int j = 0; j < 64; j++) {
        float v = t[j] * s1[j] + sh1[j];
        t[j] = v > 0.0f ? v : 0.0f;
    }
    float u[64];
#pragma unroll
    for (int j = 0; j < 64; j++) u[j] = b2[j];
    for (int k = 0; k < 64; k++) {
        float tk = t[k];
#pragma unroll
        for (int j = 0; j < 64; j++) u[j] += tk * W2[k*64 + j];
    }
#pragma unroll
    for (int j = 0; j < 64; j++) {
        float v = u[j] * as_[j] + ash[j];
        v = v > 0.0f ? v : 0.0f;
        v = v * gs[j] + gsh[j];
        u[j] = v > 0.0f ? v : 0.0f;
    }
    float4* hw = (float4*)(h + (size_t)r * 64);
#pragma unroll
    for (int q = 0; q < 16; q++) {
        float4 hv = hp[q];
        hw[q] = make_float4(hv.x + u[4*q+0], hv.y + u[4*q+1],
                            hv.z + u[4*q+2], hv.w + u[4*q+3]);
    }
}

// ---------- CSR build (once per launch; src/dst static across layers) ----------

__global__ __launch_bounds__(256) void k_count(
    const int* __restrict__ dst, int* __restrict__ deg, int E)
{
    int e = blockIdx.x * 256 + threadIdx.x;
    if (e < E) atomicAdd(&deg[dst[e]], 1);
}

// Single-workgroup exclusive scan over N entries (wave shuffle + LDS).
// Reads deg from `cursor` buffer, writes exclusive prefix into offsets AND
// back into cursor (cursor then serves as the fill pointer).
__global__ __launch_bounds__(1024) void k_scan(
    int* __restrict__ cursor, int* __restrict__ offsets, int N)
{
    __shared__ int wsum[16];
    __shared__ int carry_s;
    int tid = threadIdx.x, lane = tid & 63, wid = tid >> 6;
    if (tid == 0) carry_s = 0;
    __syncthreads();
    for (int base = 0; base < N; base += 1024) {
        int idx = base + tid;
        int v = (idx < N) ? cursor[idx] : 0;
        int x = v;
#pragma unroll
        for (int o = 1; o < 64; o <<= 1) {
            int t = __shfl_up(x, o, 64);
            if (lane >= o) x += t;
        }
        if (lane == 63) wsum[wid] = x;
        __syncthreads();
        if (wid == 0) {
            int s = (lane < 16) ? wsum[lane] : 0;
#pragma unroll
            for (int o = 1; o < 16; o <<= 1) {
                int t = __shfl_up(s, o, 64);
                if (lane >= o) s += t;
            }
            if (lane < 16) wsum[lane] = s;
        }
        __syncthreads();
        int woff  = (wid > 0) ? wsum[wid - 1] : 0;
        int carry = carry_s;
        int total = wsum[15];
        int excl  = carry + woff + x - v;
        if (idx < N) { offsets[idx] = excl; cursor[idx] = excl; }
        __syncthreads();
        if (tid == 0) carry_s = carry + total;
        __syncthreads();
        if (tid == 0 && base + 1024 >= N) offsets[N] = carry + total;
    }
}

__global__ __launch_bounds__(256) void k_fill(
    const int* __restrict__ src, const int* __restrict__ dst,
    int* __restrict__ cursor, int* __restrict__ csr_src, int E)
{
    int e = blockIdx.x * 256 + threadIdx.x;
    if (e >= E) return;
    int pos = atomicAdd(&cursor[dst[e]], 1);
    csr_src[pos] = src[e];
}

// Wave-per-node segment sum: lane f owns feature f; loops in-edges.
__global__ __launch_bounds__(256) void k_aggregate(
    const float* __restrict__ h, const int* __restrict__ csr_src,
    const int* __restrict__ offsets, float* __restrict__ neigh, int N)
{
    int node = blockIdx.x * 4 + (threadIdx.x >> 6);
    int f = threadIdx.x & 63;
    if (node >= N) return;
    int beg = offsets[node], end = offsets[node + 1];
    float acc = 0.0f;
    for (int k = beg; k < end; k++) {
        int s = csr_src[k];
        acc += h[(size_t)s * 64 + f];
    }
    neigh[(size_t)node * 64 + f] = acc;
}

// Edge score kernel (no aggregation): 16 lanes/edge.
// MODE 0: score = val; MODE 1: score += val; MODE 2: score = relu(score + val)
template <int MODE>
__global__ __launch_bounds__(256, 4) void k_edge(
    const float* __restrict__ A, const float* __restrict__ Bm,
    const float* __restrict__ e,
    const int* __restrict__ src, const int* __restrict__ dst,
    const float* __restrict__ Wc,   // rows 128..129 of pred_W1[i]: [2][64]
    const float* __restrict__ W2,   // [64]
    const float* __restrict__ b2p,  // [1]
    float* __restrict__ score, int E)
{
    const int li = threadIdx.x & 15;
    const float4 wc0 = *(const float4*)(Wc + li*4);
    const float4 wc1 = *(const float4*)(Wc + 64 + li*4);
    const float4 w2  = *(const float4*)(W2 + li*4);
    const float b2 = b2p[0];
    int g  = (blockIdx.x * 256 + threadIdx.x) >> 4;
    int ng = (gridDim.x * 256) >> 4;
    for (int idx = g; idx < E; idx += ng) {
        int s = src[idx];
        int d = dst[idx];
        float2 ev = *(const float2*)(e + 2*(size_t)idx);
        float4 a = *(const float4*)(A  + (size_t)s*64 + li*4);
        float4 b = *(const float4*)(Bm + (size_t)d*64 + li*4);
        float z0 = a.x + b.x + ev.x*wc0.x + ev.y*wc1.x; z0 = z0 > 0.f ? z0 : 0.f;
        float z1 = a.y + b.y + ev.x*wc0.y + ev.y*wc1.y; z1 = z1 > 0.f ? z1 : 0.f;
        float z2 = a.z + b.z + ev.x*wc0.z + ev.y*wc1.z; z2 = z2 > 0.f ? z2 : 0.f;
        float z3 = a.w + b.w + ev.x*wc0.w + ev.y*wc1.w; z3 = z3 > 0.f ? z3 : 0.f;
        float p = z0*w2.x + z1*w2.y + z2*w2.z + z3*w2.w;
        p += __shfl_xor(p, 1);
        p += __shfl_xor(p, 2);
        p += __shfl_xor(p, 4);
        p += __shfl_xor(p, 8);
        if (li == 0) {
            if (MODE == 0) {
                score[idx] = p + b2;
            } else if (MODE == 1) {
                score[idx] += p + b2;
            } else {
                float v = score[idx] + p + b2;
                score[idx] = v > 0.f ? v : 0.f;
            }
        }
    }
}

extern "C" void kernel_launch(void* const* d_in, const int* in_sizes, int n_in,
                              void* d_out, int out_size, void* d_ws, size_t ws_size,
                              hipStream_t stream) {
    const float* h_in  = (const float*)d_in[0];
    const float* e     = (const float*)d_in[1];
    const int*   src   = (const int*)d_in[2];
    const int*   dst   = (const int*)d_in[3];
    const float* emb_W = (const float*)d_in[4];
    const float* emb_b = (const float*)d_in[5];
    const float* eps   = (const float*)d_in[6];
    const float* mW1   = (const float*)d_in[7];
    const float* mb1   = (const float*)d_in[8];
    const float* mbs   = (const float*)d_in[9];
    const float* mbsh  = (const float*)d_in[10];
    const float* mW2   = (const float*)d_in[11];
    const float* mb2   = (const float*)d_in[12];
    const float* as_   = (const float*)d_in[13];
    const float* ash   = (const float*)d_in[14];
    const float* gs    = (const float*)d_in[15];
    const float* gsh   = (const float*)d_in[16];
    const float* pW1   = (const float*)d_in[17];
    const float* pb1   = (const float*)d_in[18];
    const float* pW2   = (const float*)d_in[19];
    const float* pb2   = (const float*)d_in[20];

    const int N = in_sizes[0] / 64;
    const int E = in_sizes[2];

    float* score = (float*)d_out;
    float* ws    = (float*)d_ws;
    float* hcur  = ws;
    float* neigh = ws + (size_t)N * 64;
    float* Abuf  = ws + 2 * (size_t)N * 64;
    float* Bbuf  = ws + 3 * (size_t)N * 64;
    int*   offsets = (int*)(ws + 4 * (size_t)N * 64);  // N+1
    int*   cursor  = offsets + (N + 1);                // N (deg, then fill ptr)
    int*   csr_src = cursor + N;                       // E

    const int nodeBlocks = (N + 255) / 256;
    const int edgeGrid   = (E + 255) / 256;
    const int edgeBlocks = 2048;
    const int aggBlocks  = (N + 3) / 4;

    // ---- CSR build (graph static; reused for all 3 aggregations) ----
    hipMemsetAsync(cursor, 0, (size_t)N * sizeof(int), stream);
    k_count<<<edgeGrid, 256, 0, stream>>>(dst, cursor, E);
    k_scan<<<1, 1024, 0, stream>>>(cursor, offsets, N);
    k_fill<<<edgeGrid, 256, 0, stream>>>(src, dst, cursor, csr_src, E);

    // h = h_in @ emb_W + emb_b
    k_matmul64<<<nodeBlocks, 256, 0, stream>>>(h_in, emb_W, emb_b, hcur, N);

    for (int i = 0; i <= L; i++) {
        const float* pw = pW1 + (size_t)i * 130 * 64;
        k_matmul64<<<nodeBlocks, 256, 0, stream>>>(hcur, pw, pb1 + i*64, Abuf, N);
        k_matmul64<<<nodeBlocks, 256, 0, stream>>>(hcur, pw + 64*64, nullptr, Bbuf, N);

        const float* Wc = pw + 128 * 64;
        const float* w2 = pW2 + (size_t)i * 64;
        const float* b2 = pb2 + i;
        if (i == 0) {
            k_edge<0><<<edgeBlocks, 256, 0, stream>>>(Abuf, Bbuf, e, src, dst,
                                                      Wc, w2, b2, score, E);
        } else if (i < L) {
            k_edge<1><<<edgeBlocks, 256, 0, stream>>>(Abuf, Bbuf, e, src, dst,
                                                      Wc, w2, b2, score, E);
        } else {
            k_edge<2><<<edgeBlocks, 256, 0, stream>>>(Abuf, Bbuf, e, src, dst,
                                                      Wc, w2, b2, score, E);
        }

        if (i < L) {
            k_aggregate<<<aggBlocks, 256, 0, stream>>>(hcur, csr_src, offsets, neigh, N);
            k_gin_update<<<nodeBlocks, 256, 0, stream>>>(
                hcur, neigh, eps + i,
                mW1 + (size_t)i*64*64, mb1 + i*64, mbs + i*64, mbsh + i*64,
                mW2 + (size_t)i*64*64, mb2 + i*64,
                as_ + i*64, ash + i*64, gs + i*64, gsh + i*64, N);
        }
    }
}

// Round 3
// 728.200 us; speedup vs baseline: 3.6587x; 1.4721x over previous
//
#include <hip/hip_runtime.h>
#include <hip/hip_bf16.h>

#define HID 64
#define L 3

typedef unsigned short ushort_t;
typedef unsigned int uint_t;

static __device__ __forceinline__ ushort_t f2bf(float f) {
    uint_t u = __float_as_uint(f);
    uint_t r = (u + 0x7FFFu + ((u >> 16) & 1u)) >> 16;   // RNE
    return (ushort_t)r;
}
static __device__ __forceinline__ float bf2f(ushort_t u) {
    return __uint_as_float(((uint_t)u) << 16);
}

// ---------------- node matmul, 16 lanes per row ----------------
// out[r][:] = in[r][:] @ W (+ bias).  OUT_BF16: store bf16 row.
template <int OUT_BF16>
__global__ __launch_bounds__(256) void k_matmul16(
    const float* __restrict__ in, const float* __restrict__ W,
    const float* __restrict__ bias, void* __restrict__ out, int N)
{
    __shared__ float xs[16][68];
    const int row16 = threadIdx.x >> 4;
    const int li    = threadIdx.x & 15;
    const int r     = blockIdx.x * 16 + row16;
    if (r >= N) return;
    float4 x4 = *(const float4*)(in + (size_t)r * 64 + 4 * li);
    xs[row16][4*li+0] = x4.x; xs[row16][4*li+1] = x4.y;
    xs[row16][4*li+2] = x4.z; xs[row16][4*li+3] = x4.w;
    float4 acc;
    if (bias) acc = *(const float4*)(bias + 4 * li);
    else      acc = make_float4(0.f, 0.f, 0.f, 0.f);
#pragma unroll
    for (int k = 0; k < 64; k++) {
        float xk = xs[row16][k];
        float4 wv = *(const float4*)(W + k * 64 + 4 * li);
        acc.x += xk * wv.x; acc.y += xk * wv.y;
        acc.z += xk * wv.z; acc.w += xk * wv.w;
    }
    if (OUT_BF16) {
        ushort_t* op = (ushort_t*)out + (size_t)r * 64 + 4 * li;
        ushort4 o;
        o.x = f2bf(acc.x); o.y = f2bf(acc.y); o.z = f2bf(acc.z); o.w = f2bf(acc.w);
        *(ushort4*)op = o;
    } else {
        *(float4*)((float*)out + (size_t)r * 64 + 4 * li) = acc;
    }
}

// ---------------- fused aggregate + GIN update, 16 lanes per row --------------
// neigh = segsum(h[src] at dst) via CSR; x = (1+eps)h + neigh;
// t = relu(bn1(x@W1+b1)); u = t@W2+b2; u = relu(bn_a(u)); u = relu(bn_g(u));
// hout = h + u   (double-buffered h)
__global__ __launch_bounds__(256) void k_gin_fused(
    const float* __restrict__ h, float* __restrict__ hout,
    const int* __restrict__ csr_src, const int* __restrict__ offsets,
    const float* __restrict__ epsp,
    const float* __restrict__ W1, const float* __restrict__ b1,
    const float* __restrict__ s1, const float* __restrict__ sh1,
    const float* __restrict__ W2, const float* __restrict__ b2,
    const float* __restrict__ as_, const float* __restrict__ ash,
    const float* __restrict__ gs, const float* __restrict__ gsh, int N)
{
    __shared__ float xs[16][68];
    __shared__ float ts[16][68];
    const int row16 = threadIdx.x >> 4;
    const int li    = threadIdx.x & 15;
    const int r     = blockIdx.x * 16 + row16;
    if (r >= N) return;

    // --- aggregation (CSR gather) ---
    int beg = offsets[r], end = offsets[r + 1];
    float4 acc = make_float4(0.f, 0.f, 0.f, 0.f);
    int k = beg;
    for (; k + 1 < end; k += 2) {
        int s0 = csr_src[k], s1i = csr_src[k + 1];
        float4 v0 = *(const float4*)(h + (size_t)s0 * 64 + 4 * li);
        float4 v1 = *(const float4*)(h + (size_t)s1i * 64 + 4 * li);
        acc.x += v0.x + v1.x; acc.y += v0.y + v1.y;
        acc.z += v0.z + v1.z; acc.w += v0.w + v1.w;
    }
    if (k < end) {
        int s0 = csr_src[k];
        float4 v0 = *(const float4*)(h + (size_t)s0 * 64 + 4 * li);
        acc.x += v0.x; acc.y += v0.y; acc.z += v0.z; acc.w += v0.w;
    }

    const float epsv = 1.0f + epsp[0];
    float4 hv = *(const float4*)(h + (size_t)r * 64 + 4 * li);
    xs[row16][4*li+0] = epsv * hv.x + acc.x;
    xs[row16][4*li+1] = epsv * hv.y + acc.y;
    xs[row16][4*li+2] = epsv * hv.z + acc.z;
    xs[row16][4*li+3] = epsv * hv.w + acc.w;

    // --- t = relu(bn1(x@W1 + b1)) ---
    float4 t = *(const float4*)(b1 + 4 * li);
#pragma unroll
    for (int kk = 0; kk < 64; kk++) {
        float xk = xs[row16][kk];
        float4 wv = *(const float4*)(W1 + kk * 64 + 4 * li);
        t.x += xk * wv.x; t.y += xk * wv.y; t.z += xk * wv.z; t.w += xk * wv.w;
    }
    {
        float4 sc = *(const float4*)(s1 + 4 * li);
        float4 sh = *(const float4*)(sh1 + 4 * li);
        t.x = t.x * sc.x + sh.x; t.x = t.x > 0.f ? t.x : 0.f;
        t.y = t.y * sc.y + sh.y; t.y = t.y > 0.f ? t.y : 0.f;
        t.z = t.z * sc.z + sh.z; t.z = t.z > 0.f ? t.z : 0.f;
        t.w = t.w * sc.w + sh.w; t.w = t.w > 0.f ? t.w : 0.f;
    }
    ts[row16][4*li+0] = t.x; ts[row16][4*li+1] = t.y;
    ts[row16][4*li+2] = t.z; ts[row16][4*li+3] = t.w;

    // --- u = t@W2 + b2; bn_a relu; bn_g relu; residual ---
    float4 u = *(const float4*)(b2 + 4 * li);
#pragma unroll
    for (int kk = 0; kk < 64; kk++) {
        float tk = ts[row16][kk];
        float4 wv = *(const float4*)(W2 + kk * 64 + 4 * li);
        u.x += tk * wv.x; u.y += tk * wv.y; u.z += tk * wv.z; u.w += tk * wv.w;
    }
    {
        float4 sc = *(const float4*)(as_ + 4 * li);
        float4 sh = *(const float4*)(ash + 4 * li);
        u.x = u.x * sc.x + sh.x; u.x = u.x > 0.f ? u.x : 0.f;
        u.y = u.y * sc.y + sh.y; u.y = u.y > 0.f ? u.y : 0.f;
        u.z = u.z * sc.z + sh.z; u.z = u.z > 0.f ? u.z : 0.f;
        u.w = u.w * sc.w + sh.w; u.w = u.w > 0.f ? u.w : 0.f;
        sc = *(const float4*)(gs + 4 * li);
        sh = *(const float4*)(gsh + 4 * li);
        u.x = u.x * sc.x + sh.x; u.x = u.x > 0.f ? u.x : 0.f;
        u.y = u.y * sc.y + sh.y; u.y = u.y > 0.f ? u.y : 0.f;
        u.z = u.z * sc.z + sh.z; u.z = u.z > 0.f ? u.z : 0.f;
        u.w = u.w * sc.w + sh.w; u.w = u.w > 0.f ? u.w : 0.f;
    }
    float4 o = make_float4(hv.x + u.x, hv.y + u.y, hv.z + u.z, hv.w + u.w);
    *(float4*)(hout + (size_t)r * 64 + 4 * li) = o;
}

// ---------------- CSR build ----------------
__global__ __launch_bounds__(256) void k_count(
    const int* __restrict__ dst, int* __restrict__ deg, int E)
{
    int e = blockIdx.x * 256 + threadIdx.x;
    if (e < E) atomicAdd(&deg[dst[e]], 1);
}

__global__ __launch_bounds__(1024) void k_scan(
    int* __restrict__ cursor, int* __restrict__ offsets, int N)
{
    __shared__ int wsum[16];
    __shared__ int carry_s;
    int tid = threadIdx.x, lane = tid & 63, wid = tid >> 6;
    if (tid == 0) carry_s = 0;
    __syncthreads();
    for (int base = 0; base < N; base += 1024) {
        int idx = base + tid;
        int v = (idx < N) ? cursor[idx] : 0;
        int x = v;
#pragma unroll
        for (int o = 1; o < 64; o <<= 1) {
            int t = __shfl_up(x, o, 64);
            if (lane >= o) x += t;
        }
        if (lane == 63) wsum[wid] = x;
        __syncthreads();
        if (wid == 0) {
            int s = (lane < 16) ? wsum[lane] : 0;
#pragma unroll
            for (int o = 1; o < 16; o <<= 1) {
                int t = __shfl_up(s, o, 64);
                if (lane >= o) s += t;
            }
            if (lane < 16) wsum[lane] = s;
        }
        __syncthreads();
        int woff  = (wid > 0) ? wsum[wid - 1] : 0;
        int carry = carry_s;
        int total = wsum[15];
        int excl  = carry + woff + x - v;
        if (idx < N) { offsets[idx] = excl; cursor[idx] = excl; }
        __syncthreads();
        if (tid == 0) carry_s = carry + total;
        __syncthreads();
        if (tid == 0 && base + 1024 >= N) offsets[N] = carry + total;
    }
}

__global__ __launch_bounds__(256) void k_fill(
    const int* __restrict__ src, const int* __restrict__ dst,
    int* __restrict__ cursor, int* __restrict__ csr_src, int E)
{
    int e = blockIdx.x * 256 + threadIdx.x;
    if (e >= E) return;
    int pos = atomicAdd(&cursor[dst[e]], 1);
    csr_src[pos] = src[e];
}

// ---------------- edge score kernel (bf16 A/B gathers) ----------------
// MODE 0: score = val; MODE 1: score += val; MODE 2: score = relu(score + val)
template <int MODE>
__global__ __launch_bounds__(256, 4) void k_edge(
    const ushort_t* __restrict__ A, const ushort_t* __restrict__ Bm,
    const float* __restrict__ e,
    const int* __restrict__ src, const int* __restrict__ dst,
    const float* __restrict__ Wc,   // rows 128..129 of pred_W1[i]: [2][64]
    const float* __restrict__ W2,   // [64]
    const float* __restrict__ b2p,  // [1]
    float* __restrict__ score, int E)
{
    const int li = threadIdx.x & 15;
    const float4 wc0 = *(const float4*)(Wc + li*4);
    const float4 wc1 = *(const float4*)(Wc + 64 + li*4);
    const float4 w2  = *(const float4*)(W2 + li*4);
    const float b2 = b2p[0];
    int g  = (blockIdx.x * 256 + threadIdx.x) >> 4;
    int ng = (gridDim.x * 256) >> 4;
    for (int idx = g; idx < E; idx += ng) {
        int s = src[idx];
        int d = dst[idx];
        float2 ev = *(const float2*)(e + 2*(size_t)idx);
        ushort4 au = *(const ushort4*)(A  + (size_t)s*64 + li*4);
        ushort4 bu = *(const ushort4*)(Bm + (size_t)d*64 + li*4);
        float z0 = bf2f(au.x) + bf2f(bu.x) + ev.x*wc0.x + ev.y*wc1.x; z0 = z0 > 0.f ? z0 : 0.f;
        float z1 = bf2f(au.y) + bf2f(bu.y) + ev.x*wc0.y + ev.y*wc1.y; z1 = z1 > 0.f ? z1 : 0.f;
        float z2 = bf2f(au.z) + bf2f(bu.z) + ev.x*wc0.z + ev.y*wc1.z; z2 = z2 > 0.f ? z2 : 0.f;
        float z3 = bf2f(au.w) + bf2f(bu.w) + ev.x*wc0.w + ev.y*wc1.w; z3 = z3 > 0.f ? z3 : 0.f;
        float p = z0*w2.x + z1*w2.y + z2*w2.z + z3*w2.w;
        p += __shfl_xor(p, 1);
        p += __shfl_xor(p, 2);
        p += __shfl_xor(p, 4);
        p += __shfl_xor(p, 8);
        if (li == 0) {
            if (MODE == 0) {
                score[idx] = p + b2;
            } else if (MODE == 1) {
                score[idx] += p + b2;
            } else {
                float v = score[idx] + p + b2;
                score[idx] = v > 0.f ? v : 0.f;
            }
        }
    }
}

extern "C" void kernel_launch(void* const* d_in, const int* in_sizes, int n_in,
                              void* d_out, int out_size, void* d_ws, size_t ws_size,
                              hipStream_t stream) {
    const float* h_in  = (const float*)d_in[0];
    const float* e     = (const float*)d_in[1];
    const int*   src   = (const int*)d_in[2];
    const int*   dst   = (const int*)d_in[3];
    const float* emb_W = (const float*)d_in[4];
    const float* emb_b = (const float*)d_in[5];
    const float* eps   = (const float*)d_in[6];
    const float* mW1   = (const float*)d_in[7];
    const float* mb1   = (const float*)d_in[8];
    const float* mbs   = (const float*)d_in[9];
    const float* mbsh  = (const float*)d_in[10];
    const float* mW2   = (const float*)d_in[11];
    const float* mb2   = (const float*)d_in[12];
    const float* as_   = (const float*)d_in[13];
    const float* ash   = (const float*)d_in[14];
    const float* gs    = (const float*)d_in[15];
    const float* gsh   = (const float*)d_in[16];
    const float* pW1   = (const float*)d_in[17];
    const float* pb1   = (const float*)d_in[18];
    const float* pW2   = (const float*)d_in[19];
    const float* pb2   = (const float*)d_in[20];

    const int N = in_sizes[0] / 64;
    const int E = in_sizes[2];

    float* score = (float*)d_out;

    char* wp = (char*)d_ws;
    float* h0 = (float*)wp;         wp += (size_t)N * 64 * 4;
    float* h1 = (float*)wp;         wp += (size_t)N * 64 * 4;
    ushort_t* Abuf = (ushort_t*)wp; wp += (size_t)N * 64 * 2;
    ushort_t* Bbuf = (ushort_t*)wp; wp += (size_t)N * 64 * 2;
    int* offsets = (int*)wp;        wp += (size_t)(N + 1) * 4;
    int* cursor  = (int*)wp;        wp += (size_t)N * 4;
    int* csr_src = (int*)wp;        // E ints

    const int rowBlocks = (N + 15) / 16;
    const int edgeGrid  = (E + 255) / 256;
    const int edgeBlocks = 2048;

    // ---- CSR build (graph static; reused for all 3 aggregations) ----
    hipMemsetAsync(cursor, 0, (size_t)N * sizeof(int), stream);
    k_count<<<edgeGrid, 256, 0, stream>>>(dst, cursor, E);
    k_scan<<<1, 1024, 0, stream>>>(cursor, offsets, N);
    k_fill<<<edgeGrid, 256, 0, stream>>>(src, dst, cursor, csr_src, E);

    // h = h_in @ emb_W + emb_b
    k_matmul16<0><<<rowBlocks, 256, 0, stream>>>(h_in, emb_W, emb_b, h0, N);

    float* hcur = h0;
    float* hnext = h1;

    for (int i = 0; i <= L; i++) {
        const float* pw = pW1 + (size_t)i * 130 * 64;
        k_matmul16<1><<<rowBlocks, 256, 0, stream>>>(hcur, pw,          pb1 + i*64, Abuf, N);
        k_matmul16<1><<<rowBlocks, 256, 0, stream>>>(hcur, pw + 64*64,  nullptr,    Bbuf, N);

        const float* Wc = pw + 128 * 64;
        const float* w2 = pW2 + (size_t)i * 64;
        const float* b2 = pb2 + i;
        if (i == 0) {
            k_edge<0><<<edgeBlocks, 256, 0, stream>>>(Abuf, Bbuf, e, src, dst,
                                                      Wc, w2, b2, score, E);
        } else if (i < L) {
            k_edge<1><<<edgeBlocks, 256, 0, stream>>>(Abuf, Bbuf, e, src, dst,
                                                      Wc, w2, b2, score, E);
        } else {
            k_edge<2><<<edgeBlocks, 256, 0, stream>>>(Abuf, Bbuf, e, src, dst,
                                                      Wc, w2, b2, score, E);
        }

        if (i < L) {
            k_gin_fused<<<rowBlocks, 256, 0, stream>>>(
                hcur, hnext, csr_src, offsets, eps + i,
                mW1 + (size_t)i*64*64, mb1 + i*64, mbs + i*64, mbsh + i*64,
                mW2 + (size_t)i*64*64, mb2 + i*64,
                as_ + i*64, ash + i*64, gs + i*64, gsh + i*64, N);
            float* tmp = hcur; hcur = hnext; hnext = tmp;
        }
    }
}